// Round 1
// baseline (2164.765 us; speedup 1.0000x reference)
//
#include <hip/hip_runtime.h>

// NearestNeighbor: b=8, d=256, n=m=4096, fp32 in, (matches int32, scores f32) out.
// Round 1: fused fp32 tiled GEMM + running top-2, two directions + mutual check.

constexpr int BATCH = 8;
constexpr int DDIM  = 256;
constexpr int NM    = 4096;
constexpr int BN    = 64;   // rows per block
constexpr int BM    = 64;   // cols per tile
constexpr int KB    = 16;   // k-slice per LDS stage

__device__ __forceinline__ bool better(float v, int i, float w, int j) {
  // strict ordering with lower-index tie-break (matches jax.lax.top_k)
  return (v > w) || (v == w && i < j);
}

__global__ __launch_bounds__(256)
void nn_top2_kernel(const float* __restrict__ A,   // [b, d, N] rows of sim
                    const float* __restrict__ B,   // [b, d, M] cols of sim
                    int* __restrict__ matches, float* __restrict__ scores)
{
  __shared__ float As[KB][BN];
  __shared__ float Bs[KB][BM];

  const int blk = blockIdx.x;
  const int b   = blk & 7;        // XCD-pinned batch: each XCD's L2 caches one batch's B (4 MB)
  const int rb  = blk >> 3;
  const int row_base = rb * BN;

  const int tid = threadIdx.x;
  const int ty  = tid >> 4;       // 0..15, owns rows ty*4..ty*4+3
  const int tx  = tid & 15;       // 0..15, owns cols tx*4..tx*4+3 (per tile)

  const float* Ab = A + (size_t)b * DDIM * NM;
  const float* Bb = B + (size_t)b * DDIM * NM;

  // per-lane running top-2 over this lane's column subset, for 4 rows
  float rv1[4], rv2[4];
  int   ri1[4], ri2[4];
  #pragma unroll
  for (int i = 0; i < 4; ++i) { rv1[i] = -1e30f; rv2[i] = -1e30f; ri1[i] = 0x7fffffff; ri2[i] = 0x7fffffff; }

  const int lkk = tid >> 4;        // staging: k-row 0..15
  const int lc  = (tid & 15) * 4;  // staging: col offset, float4

  for (int mt = 0; mt < NM; mt += BM) {
    float acc[4][4];
    #pragma unroll
    for (int i = 0; i < 4; ++i)
      #pragma unroll
      for (int j = 0; j < 4; ++j) acc[i][j] = 0.f;

    for (int k0 = 0; k0 < DDIM; k0 += KB) {
      __syncthreads();   // protect LDS from previous stage's readers
      *(float4*)(&As[lkk][lc]) = *(const float4*)(&Ab[(size_t)(k0 + lkk) * NM + row_base + lc]);
      *(float4*)(&Bs[lkk][lc]) = *(const float4*)(&Bb[(size_t)(k0 + lkk) * NM + mt + lc]);
      __syncthreads();
      #pragma unroll
      for (int kk = 0; kk < KB; ++kk) {
        const float4 av = *(const float4*)(&As[kk][ty * 4]);
        const float4 bv = *(const float4*)(&Bs[kk][tx * 4]);
        const float a[4]  = {av.x, av.y, av.z, av.w};
        const float bb[4] = {bv.x, bv.y, bv.z, bv.w};
        #pragma unroll
        for (int i = 0; i < 4; ++i)
          #pragma unroll
          for (int j = 0; j < 4; ++j)
            acc[i][j] = fmaf(a[i], bb[j], acc[i][j]);
      }
    }

    // fold tile into per-lane running top-2 (columns processed in increasing index order)
    #pragma unroll
    for (int i = 0; i < 4; ++i) {
      #pragma unroll
      for (int j = 0; j < 4; ++j) {
        const float c   = acc[i][j];
        const int   idx = mt + tx * 4 + j;
        if (c > rv1[i])      { rv2[i] = rv1[i]; ri2[i] = ri1[i]; rv1[i] = c; ri1[i] = idx; }
        else if (c > rv2[i]) { rv2[i] = c; ri2[i] = idx; }
      }
    }
  }

  // merge top-2 across the 16 lanes of this row-group (consecutive lanes, same wave)
  #pragma unroll
  for (int off = 1; off < 16; off <<= 1) {
    #pragma unroll
    for (int i = 0; i < 4; ++i) {
      const float w1 = __shfl_xor(rv1[i], off);
      const int   j1 = __shfl_xor(ri1[i], off);
      const float w2 = __shfl_xor(rv2[i], off);
      const int   j2 = __shfl_xor(ri2[i], off);
      if (better(w1, j1, rv1[i], ri1[i])) {
        if (better(rv1[i], ri1[i], w2, j2)) { rv2[i] = rv1[i]; ri2[i] = ri1[i]; }
        else                                { rv2[i] = w2;     ri2[i] = j2;     }
        rv1[i] = w1; ri1[i] = j1;
      } else if (better(w1, j1, rv2[i], ri2[i])) {
        rv2[i] = w1; ri2[i] = j1;
      }
    }
  }

  if (tx == 0) {
    #pragma unroll
    for (int i = 0; i < 4; ++i) {
      const int row = row_base + ty * 4 + i;
      const float d0 = 2.f * (1.f - rv1[i]);
      const float d1 = 2.f * (1.f - rv2[i]);
      const bool ok = d0 <= 0.64f * d1;   // 0.8^2 Lowe ratio
      matches[(size_t)b * NM + row] = ok ? ri1[i] : -1;
      scores [(size_t)b * NM + row] = ok ? (rv1[i] + 1.f) * 0.5f : 0.f;
    }
  }
}

__global__ void finalize_kernel(const int* __restrict__ m0, const float* __restrict__ s0,
                                const int* __restrict__ m1, float* __restrict__ out)
{
  const int idx = blockIdx.x * blockDim.x + threadIdx.x;
  if (idx >= BATCH * NM) return;
  const int b = idx >> 12;
  const int n = idx & (NM - 1);
  const int mm = m0[idx];
  int res = -1;
  if (mm > -1 && m1[((size_t)b << 12) + mm] == n) res = mm;
  out[idx] = (float)res;              // matches0 as float (exactly representable)
  out[BATCH * NM + idx] = s0[idx];    // scores0 (NOT masked by mutual check, per reference)
}

extern "C" void kernel_launch(void* const* d_in, const int* in_sizes, int n_in,
                              void* d_out, int out_size, void* d_ws, size_t ws_size,
                              hipStream_t stream)
{
  const float* d0 = (const float*)d_in[0];
  const float* d1 = (const float*)d_in[1];
  float* out = (float*)d_out;

  const size_t PLANE = (size_t)BATCH * NM;          // 32768 elements
  int*   m0 = (int*)  d_ws;
  float* s0 = (float*)((char*)d_ws + PLANE * 4);
  int*   m1 = (int*)  ((char*)d_ws + PLANE * 8);
  float* s1 = (float*)((char*)d_ws + PLANE * 12);

  dim3 block(256);
  dim3 grid(BATCH * (NM / BN));   // 512 blocks

  nn_top2_kernel<<<grid, block, 0, stream>>>(d0, d1, m0, s0);   // row direction
  nn_top2_kernel<<<grid, block, 0, stream>>>(d1, d0, m1, s1);   // column direction
  finalize_kernel<<<(int)((PLANE + 255) / 256), 256, 0, stream>>>(m0, s0, m1, out);
}

// Round 2
// 180.669 us; speedup vs baseline: 11.9819x; 11.9819x over previous
//
#include <hip/hip_runtime.h>

// NearestNeighbor b=8, d=256, n=m=4096.
// Round 2: bf16 MFMA fused GEMM+top2. prep(transpose->bf16) -> pass x2 -> merge -> finalize.

typedef unsigned int uint;
typedef unsigned short ushort_t;
typedef short bf16x8 __attribute__((ext_vector_type(8)));
typedef float f32x4 __attribute__((ext_vector_type(4)));

constexpr int B_ = 8, D_ = 256, N_ = 4096;
constexpr int BM = 128;                      // rows per block
constexpr int BNT = 128;                     // cols per tile iteration
constexpr int BK = 64;                       // k per LDS stage
constexpr int CSPLIT = 4;                    // column split (occupancy)
constexpr int MT_ITERS = (N_ / CSPLIT) / BNT;  // 8
constexpr int KSTEPS = D_ / BK;              // 4

// workspace layout (bytes)
constexpr size_t SZ_PANEL = (size_t)B_ * N_ * D_ * 2;           // 16.78 MB
constexpr size_t OFF_AT = 0;
constexpr size_t OFF_BT = SZ_PANEL;
constexpr size_t SZ_PART = (size_t)CSPLIT * B_ * N_ * 8;        // 1 MB
constexpr size_t OFF_P0 = 2 * SZ_PANEL;
constexpr size_t OFF_P1 = OFF_P0 + SZ_PART;
constexpr size_t OFF_M0 = OFF_P1 + SZ_PART;
constexpr size_t OFF_S0 = OFF_M0 + (size_t)B_ * N_ * 4;
constexpr size_t OFF_M1 = OFF_S0 + (size_t)B_ * N_ * 4;

__device__ __forceinline__ ushort_t f2bf(float f) {   // RNE f32->bf16
  uint u = __float_as_uint(f);
  return (ushort_t)((u + 0x7FFFu + ((u >> 16) & 1u)) >> 16);
}

__device__ __forceinline__ void glds16(const void* g, void* l) {
  __builtin_amdgcn_global_load_lds(
      (const __attribute__((address_space(1))) void*)(uintptr_t)(g),
      (__attribute__((address_space(3))) void*)(uint32_t)(uintptr_t)(l),
      16, 0, 0);
}

// ---- transpose + convert: [b][256][4096] f32 -> [b][4096][256] bf16 ----
__global__ __launch_bounds__(256)
void prep_kernel(const float* __restrict__ in0, const float* __restrict__ in1,
                 ushort_t* __restrict__ At, ushort_t* __restrict__ Bt)
{
  __shared__ ushort_t tile[32][33];
  const int z = blockIdx.z;
  const float* src = (z < 8) ? in0 : in1;
  ushort_t* dst = (z < 8) ? At : Bt;
  const int b = z & 7;
  const int k0 = blockIdx.y * 32, n0 = blockIdx.x * 32;
  const int t = threadIdx.x;
  const int kl = t >> 3, n4 = (t & 7) * 4;
  const float4 v = *(const float4*)(src + ((size_t)b * D_ + k0 + kl) * N_ + n0 + n4);
  tile[kl][n4 + 0] = f2bf(v.x); tile[kl][n4 + 1] = f2bf(v.y);
  tile[kl][n4 + 2] = f2bf(v.z); tile[kl][n4 + 3] = f2bf(v.w);
  __syncthreads();
  const int nl = t >> 3, k4 = (t & 7) * 4;
  ushort4 o;
  o.x = tile[k4 + 0][nl]; o.y = tile[k4 + 1][nl];
  o.z = tile[k4 + 2][nl]; o.w = tile[k4 + 3][nl];
  *(ushort4*)(dst + ((size_t)b * N_ + n0 + nl) * D_ + k0 + k4) = o;
}

// ---- fused GEMM + running top-2 ----
// A,B: [b][4096][256] bf16 row-major. Block: 128 rows x 1024 cols scan, K=256.
// LDS tiles [128][64] bf16 with XOR-16B swizzle (pre-swizzled global source).
__global__ __launch_bounds__(256, 2)
void nn_pass(const ushort_t* __restrict__ A, const ushort_t* __restrict__ Bp,
             uint2* __restrict__ part)
{
  __shared__ ushort_t As[BM * BK];   // 16 KB
  __shared__ ushort_t Bs[BNT * BK];  // 16 KB

  const int t = threadIdx.x;
  const int bid = blockIdx.x;
  const int b = bid & 7;                   // XCD-pinned batch
  const int rowblk = (bid >> 3) & 31;
  const int cs = bid >> 8;
  const size_t bOff = (size_t)b * N_ * D_;
  const int r0 = rowblk * BM;
  const int c0 = cs * (N_ / CSPLIT);

  const int l = t & 63, wid = t >> 6;
  const int wm = wid >> 1, wn = wid & 1;
  const int l15 = l & 15, g = l >> 4;
  const uint swz = (uint)(l & 7) << 4;     // read-side XOR (bytes)

  // staging: 4 chunks of 16B per operand per thread per K-step
  const ushort_t* srcA[4]; const ushort_t* srcB[4]; int ldsq[4];
  #pragma unroll
  for (int i = 0; i < 4; ++i) {
    const int q = i * 256 + t;
    const int r = q >> 3;
    const int kfl = (((q & 7) ^ (r & 7)) << 3);  // pre-swizzled source k (elements)
    srcA[i] = A  + bOff + (size_t)(r0 + r) * D_ + kfl;
    srcB[i] = Bp + bOff + (size_t)(c0 + r) * D_ + kfl;
    ldsq[i] = q * 16;
  }

  const float NEG = __uint_as_float(0xFF800000u);  // -inf
  float s1[4][4], s2[4][4];
  #pragma unroll
  for (int mi = 0; mi < 4; ++mi)
    #pragma unroll
    for (int rg = 0; rg < 4; ++rg) { s1[mi][rg] = NEG; s2[mi][rg] = NEG; }

  for (int mt = 0; mt < MT_ITERS; ++mt) {
    f32x4 acc[4][4];
    #pragma unroll
    for (int mi = 0; mi < 4; ++mi)
      #pragma unroll
      for (int ni = 0; ni < 4; ++ni) acc[mi][ni] = (f32x4){0.f, 0.f, 0.f, 0.f};

    const size_t mtOff = (size_t)mt * BNT * D_;

    for (int ks = 0; ks < KSTEPS; ++ks) {
      __syncthreads();                       // prev tile readers done
      #pragma unroll
      for (int i = 0; i < 4; ++i) {
        glds16(srcA[i] + ks * BK,         (char*)As + ldsq[i]);
        glds16(srcB[i] + mtOff + ks * BK, (char*)Bs + ldsq[i]);
      }
      __syncthreads();                       // compiler drains vmcnt(0) here

      #pragma unroll
      for (int kk = 0; kk < 2; ++kk) {
        const uint kb = (uint)(kk * 64 + g * 16) ^ swz;
        bf16x8 a[4], bb[4];
        #pragma unroll
        for (int mi = 0; mi < 4; ++mi) {
          const int arow = wm * 64 + mi * 16 + l15;
          a[mi] = *(const bf16x8*)((const char*)As + arow * (BK * 2) + kb);
          const int brow = wn * 64 + mi * 16 + l15;
          bb[mi] = *(const bf16x8*)((const char*)Bs + brow * (BK * 2) + kb);
        }
        #pragma unroll
        for (int mi = 0; mi < 4; ++mi)
          #pragma unroll
          for (int ni = 0; ni < 4; ++ni)
            acc[mi][ni] = __builtin_amdgcn_mfma_f32_16x16x32_bf16(a[mi], bb[ni], acc[mi][ni], 0, 0, 0);
      }
    }

    // fold tile into per-lane top-2 of packed keys (val | (4095-col) in low 12 bits)
    #pragma unroll
    for (int ni = 0; ni < 4; ++ni) {
      const uint tag = (uint)(4095 - (c0 + mt * BNT + wn * 64 + ni * 16 + l15));
      #pragma unroll
      for (int mi = 0; mi < 4; ++mi) {
        #pragma unroll
        for (int rg = 0; rg < 4; ++rg) {
          const uint kb2 = (__float_as_uint(acc[mi][ni][rg]) & 0xFFFFF000u) | tag;
          const float key = __uint_as_float(kb2);
          const float ns2 = fmaxf(s2[mi][rg], fminf(s1[mi][rg], key));
          s1[mi][rg] = fmaxf(s1[mi][rg], key);
          s2[mi][rg] = ns2;
        }
      }
    }
  }

  // merge top-2 across the 16 lanes of each row-group
  #pragma unroll
  for (int off = 8; off >= 1; off >>= 1) {
    #pragma unroll
    for (int mi = 0; mi < 4; ++mi)
      #pragma unroll
      for (int rg = 0; rg < 4; ++rg) {
        const float o1 = __shfl_xor(s1[mi][rg], off);
        const float o2 = __shfl_xor(s2[mi][rg], off);
        const float t1 = fmaxf(s1[mi][rg], o1);
        float t2 = fmaxf(s2[mi][rg], fminf(s1[mi][rg], o1));
        t2 = fmaxf(t2, o2);                  // o2 <= o1 <= t1
        s1[mi][rg] = t1; s2[mi][rg] = t2;
      }
  }

  if (l15 == 0) {
    #pragma unroll
    for (int mi = 0; mi < 4; ++mi)
      #pragma unroll
      for (int rg = 0; rg < 4; ++rg) {
        const int row = r0 + wm * 64 + mi * 16 + g * 4 + rg;
        part[(size_t)(cs * B_ + b) * N_ + row] =
            make_uint2(__float_as_uint(s1[mi][rg]), __float_as_uint(s2[mi][rg]));
      }
  }
}

// ---- merge col-split partials, ratio test ----
__global__ __launch_bounds__(256)
void merge_kernel(const uint2* __restrict__ p0, const uint2* __restrict__ p1,
                  int* __restrict__ m0, float* __restrict__ s0, int* __restrict__ m1)
{
  const int tid = blockIdx.x * 256 + threadIdx.x;
  if (tid >= 2 * B_ * N_) return;
  const int dir = tid >> 15;
  const int i = tid & (B_ * N_ - 1);
  const uint2* p = dir ? p1 : p0;
  float s1 = __uint_as_float(0xFF800000u), s2 = s1;
  #pragma unroll
  for (int c = 0; c < CSPLIT; ++c) {
    const uint2 v = p[(size_t)c * B_ * N_ + i];
    const float o1 = __uint_as_float(v.x), o2 = __uint_as_float(v.y);
    const float t1 = fmaxf(s1, o1);
    float t2 = fmaxf(s2, fminf(s1, o1));
    t2 = fmaxf(t2, o2);
    s1 = t1; s2 = t2;
  }
  const uint k1 = __float_as_uint(s1), k2 = __float_as_uint(s2);
  const int idx = 4095 - (int)(k1 & 0xFFFu);
  const float v1 = __uint_as_float(k1 & 0xFFFFF000u);
  const float v2 = __uint_as_float(k2 & 0xFFFFF000u);
  const bool ok = (1.0f - v1) <= 0.64f * (1.0f - v2);   // Lowe 0.8^2
  if (dir == 0) { m0[i] = ok ? idx : -1; s0[i] = ok ? (v1 + 1.0f) * 0.5f : 0.0f; }
  else          { m1[i] = ok ? idx : -1; }
}

// ---- mutual check + output ----
__global__ __launch_bounds__(256)
void finalize_kernel(const int* __restrict__ m0, const float* __restrict__ s0,
                     const int* __restrict__ m1, float* __restrict__ out)
{
  const int idx = blockIdx.x * 256 + threadIdx.x;
  if (idx >= B_ * N_) return;
  const int b = idx >> 12;
  const int n = idx & (N_ - 1);
  const int mm = m0[idx];
  int res = -1;
  if (mm > -1 && m1[((size_t)b << 12) + mm] == n) res = mm;
  out[idx] = (float)res;
  out[B_ * N_ + idx] = s0[idx];
}

extern "C" void kernel_launch(void* const* d_in, const int* in_sizes, int n_in,
                              void* d_out, int out_size, void* d_ws, size_t ws_size,
                              hipStream_t stream)
{
  const float* d0 = (const float*)d_in[0];
  const float* d1 = (const float*)d_in[1];
  float* out = (float*)d_out;

  ushort_t* At = (ushort_t*)((char*)d_ws + OFF_AT);
  ushort_t* Bt = (ushort_t*)((char*)d_ws + OFF_BT);
  uint2* P0 = (uint2*)((char*)d_ws + OFF_P0);
  uint2* P1 = (uint2*)((char*)d_ws + OFF_P1);
  int*   m0 = (int*)  ((char*)d_ws + OFF_M0);
  float* s0 = (float*)((char*)d_ws + OFF_S0);
  int*   m1 = (int*)  ((char*)d_ws + OFF_M1);

  prep_kernel<<<dim3(N_ / 32, D_ / 32, 16), 256, 0, stream>>>(d0, d1, At, Bt);
  nn_pass<<<dim3(B_ * (N_ / BM) * CSPLIT), 256, 0, stream>>>(At, Bt, P0);
  nn_pass<<<dim3(B_ * (N_ / BM) * CSPLIT), 256, 0, stream>>>(Bt, At, P1);
  merge_kernel<<<dim3(2 * B_ * N_ / 256), 256, 0, stream>>>(P0, P1, m0, s0, m1);
  finalize_kernel<<<dim3(B_ * N_ / 256), 256, 0, stream>>>(m0, s0, m1, out);
}

// Round 3
// 131.340 us; speedup vs baseline: 16.4822x; 1.3756x over previous
//
#include <hip/hip_runtime.h>

// NearestNeighbor b=8, d=256, n=m=4096.
// Round 3: SINGLE fused GEMM computing BOTH row- and col-direction top-2.
// prep(transpose->bf16) -> nn_pass (1x) -> merge -> finalize.

typedef unsigned int uint;
typedef unsigned short ushort_t;
typedef short bf16x8 __attribute__((ext_vector_type(8)));
typedef float f32x4 __attribute__((ext_vector_type(4)));

constexpr int B_ = 8, D_ = 256, N_ = 4096;
constexpr int BM = 128;                        // rows per block
constexpr int BNT = 128;                       // cols per tile iteration
constexpr int BK = 64;                         // k per LDS stage
constexpr int CSPLIT = 4;                      // column split
constexpr int MT_ITERS = (N_ / CSPLIT) / BNT;  // 8
constexpr int KSTEPS = D_ / BK;                // 4

// workspace layout (bytes)
constexpr size_t SZ_PANEL = (size_t)B_ * N_ * D_ * 2;   // 16.78 MB each
constexpr size_t OFF_AT = 0;
constexpr size_t OFF_BT = SZ_PANEL;
constexpr size_t OFF_PR = 2 * SZ_PANEL;                 // row partials: 16 slots
constexpr size_t SZ_PR  = (size_t)16 * B_ * N_ * 8;     // 4.2 MB
constexpr size_t OFF_PC = OFF_PR + SZ_PR;               // col partials: 32 slots
constexpr size_t SZ_PC  = (size_t)32 * B_ * N_ * 8;     // 8.4 MB
constexpr size_t OFF_M0 = OFF_PC + SZ_PC;
constexpr size_t OFF_S0 = OFF_M0 + (size_t)B_ * N_ * 4;
constexpr size_t OFF_M1 = OFF_S0 + (size_t)B_ * N_ * 4;

__device__ __forceinline__ ushort_t f2bf(float f) {   // RNE f32->bf16
  uint u = __float_as_uint(f);
  return (ushort_t)((u + 0x7FFFu + ((u >> 16) & 1u)) >> 16);
}

__device__ __forceinline__ void glds16(const void* g, void* l) {
  __builtin_amdgcn_global_load_lds(
      (const __attribute__((address_space(1))) void*)(uintptr_t)(g),
      (__attribute__((address_space(3))) void*)(uint32_t)(uintptr_t)(l),
      16, 0, 0);
}

__device__ __forceinline__ float packkey(float v, uint mask, uint tag) {
  return __uint_as_float((__float_as_uint(v) & mask) | tag);
}

// top-2 update with invariant s1 >= s2 (v_max + v_med3)
__device__ __forceinline__ void top2(float& s1, float& s2, float k) {
#if __has_builtin(__builtin_amdgcn_fmed3f)
  const float m = __builtin_amdgcn_fmed3f(s1, s2, k);
#else
  const float m = fmaxf(s2, fminf(s1, k));
#endif
  s1 = fmaxf(s1, k);
  s2 = m;
}

// merge two sorted top-2 pairs
__device__ __forceinline__ void top2merge(float& s1, float& s2, float o1, float o2) {
  const float lo = fminf(s1, o1);
  s1 = fmaxf(s1, o1);
  s2 = fmaxf(lo, fmaxf(s2, o2));
}

// ---- transpose + convert: [b][256][4096] f32 -> [b][4096][256] bf16 ----
__global__ __launch_bounds__(256)
void prep_kernel(const float* __restrict__ in0, const float* __restrict__ in1,
                 ushort_t* __restrict__ At, ushort_t* __restrict__ Bt)
{
  __shared__ ushort_t tile[32][33];
  const int z = blockIdx.z;
  const float* src = (z < 8) ? in0 : in1;
  ushort_t* dst = (z < 8) ? At : Bt;
  const int b = z & 7;
  const int k0 = blockIdx.y * 32, n0 = blockIdx.x * 32;
  const int t = threadIdx.x;
  const int kl = t >> 3, n4 = (t & 7) * 4;
  const float4 v = *(const float4*)(src + ((size_t)b * D_ + k0 + kl) * N_ + n0 + n4);
  tile[kl][n4 + 0] = f2bf(v.x); tile[kl][n4 + 1] = f2bf(v.y);
  tile[kl][n4 + 2] = f2bf(v.z); tile[kl][n4 + 3] = f2bf(v.w);
  __syncthreads();
  const int nl = t >> 3, k4 = (t & 7) * 4;
  ushort4 o;
  o.x = tile[k4 + 0][nl]; o.y = tile[k4 + 1][nl];
  o.z = tile[k4 + 2][nl]; o.w = tile[k4 + 3][nl];
  *(ushort4*)(dst + ((size_t)b * N_ + n0 + nl) * D_ + k0 + k4) = o;
}

// ---- single fused GEMM + dual-direction top-2 ----
// Wave mapping 1M x 4N: wave wn owns 128 rows x 32 cols of each 128x128 tile.
// Row keys: 22 high bits | 10-bit (1023 - local col within 1024-col scan).
// Col keys: 24 high bits | 7-bit (127 - local row within 128-row block).
__global__ __launch_bounds__(256, 2)
void nn_pass(const ushort_t* __restrict__ A, const ushort_t* __restrict__ Bp,
             uint2* __restrict__ partR, uint2* __restrict__ partC)
{
  __shared__ ushort_t As[BM * BK];   // 16 KB
  __shared__ ushort_t Bs[BNT * BK];  // 16 KB

  const int t = threadIdx.x;
  const int bid = blockIdx.x;
  const int b = bid & 7;                   // XCD-pinned batch
  const int rb = (bid >> 3) & 31;
  const int cs = bid >> 8;
  const size_t bOff = (size_t)b * N_ * D_;
  const int r0 = rb * BM;
  const int c0 = cs * (N_ / CSPLIT);

  const int l = t & 63, wn = t >> 6;       // 4 waves: full rows, 32-col slice
  const int l15 = l & 15, g = l >> 4;
  const uint swz = (uint)(l & 7) << 4;     // read-side XOR (bytes)

  // staging: 4 chunks of 16B per operand per thread per K-step (pre-swizzled src)
  const ushort_t* srcA[4]; const ushort_t* srcB[4]; int ldsq[4];
  #pragma unroll
  for (int i = 0; i < 4; ++i) {
    const int q = i * 256 + t;
    const int r = q >> 3;
    const int kfl = (((q & 7) ^ (r & 7)) << 3);
    srcA[i] = A  + bOff + (size_t)(r0 + r) * D_ + kfl;
    srcB[i] = Bp + bOff + (size_t)(c0 + r) * D_ + kfl;
    ldsq[i] = q * 16;
  }

  const float NEG = __uint_as_float(0xFF800000u);  // -inf
  float rs1[8][4], rs2[8][4];
  #pragma unroll
  for (int mi = 0; mi < 8; ++mi)
    #pragma unroll
    for (int rg = 0; rg < 4; ++rg) { rs1[mi][rg] = NEG; rs2[mi][rg] = NEG; }

  for (int mt = 0; mt < MT_ITERS; ++mt) {
    f32x4 acc[8][2];
    #pragma unroll
    for (int mi = 0; mi < 8; ++mi)
      #pragma unroll
      for (int ni = 0; ni < 2; ++ni) acc[mi][ni] = (f32x4){0.f, 0.f, 0.f, 0.f};

    const size_t mtOff = (size_t)mt * BNT * D_;

    for (int ks = 0; ks < KSTEPS; ++ks) {
      __syncthreads();
      #pragma unroll
      for (int i = 0; i < 4; ++i) {
        glds16(srcA[i] + ks * BK,         (char*)As + ldsq[i]);
        glds16(srcB[i] + mtOff + ks * BK, (char*)Bs + ldsq[i]);
      }
      __syncthreads();

      #pragma unroll
      for (int kk = 0; kk < 2; ++kk) {
        const uint kb = (uint)(kk * 64 + g * 16) ^ swz;
        bf16x8 a[8], bb[2];
        #pragma unroll
        for (int mi = 0; mi < 8; ++mi)
          a[mi] = *(const bf16x8*)((const char*)As + (mi * 16 + l15) * (BK * 2) + kb);
        #pragma unroll
        for (int ni = 0; ni < 2; ++ni)
          bb[ni] = *(const bf16x8*)((const char*)Bs + (wn * 32 + ni * 16 + l15) * (BK * 2) + kb);
        #pragma unroll
        for (int mi = 0; mi < 8; ++mi)
          #pragma unroll
          for (int ni = 0; ni < 2; ++ni)
            acc[mi][ni] = __builtin_amdgcn_mfma_f32_16x16x32_bf16(a[mi], bb[ni], acc[mi][ni], 0, 0, 0);
      }
    }

    // ---- row-direction fold (state persists across mt) ----
    const int colbase = mt * BNT + wn * 32;
    const uint tagc0 = (uint)(1023 - (colbase + l15));
    const uint tagc1 = (uint)(1023 - (colbase + 16 + l15));
    #pragma unroll
    for (int mi = 0; mi < 8; ++mi)
      #pragma unroll
      for (int rg = 0; rg < 4; ++rg) {
        top2(rs1[mi][rg], rs2[mi][rg], packkey(acc[mi][0][rg], 0xFFFFFC00u, tagc0));
        top2(rs1[mi][rg], rs2[mi][rg], packkey(acc[mi][1][rg], 0xFFFFFC00u, tagc1));
      }

    // ---- col-direction fold (per-tile, merged across g-groups) ----
    const uint tgb = (uint)(127 - g * 4);
    #pragma unroll
    for (int ni = 0; ni < 2; ++ni) {
      float c1 = NEG, c2 = NEG;
      #pragma unroll
      for (int mi = 0; mi < 8; ++mi)
        #pragma unroll
        for (int rg = 0; rg < 4; ++rg)
          top2(c1, c2, packkey(acc[mi][ni][rg], 0xFFFFFF00u, tgb - (uint)(mi * 16 + rg)));
      #pragma unroll
      for (int off = 16; off <= 32; off <<= 1) {
        const float o1 = __shfl_xor(c1, off);
        const float o2 = __shfl_xor(c2, off);
        top2merge(c1, c2, o1, o2);
      }
      if (g == 0)
        partC[((size_t)rb * B_ + b) * N_ + c0 + colbase + ni * 16 + l15] =
            make_uint2(__float_as_uint(c1), __float_as_uint(c2));
    }
  }

  // ---- row merge across 16 column-lanes, write per-(cs,wn) partials ----
  #pragma unroll
  for (int off = 1; off < 16; off <<= 1) {
    #pragma unroll
    for (int mi = 0; mi < 8; ++mi)
      #pragma unroll
      for (int rg = 0; rg < 4; ++rg) {
        const float o1 = __shfl_xor(rs1[mi][rg], off);
        const float o2 = __shfl_xor(rs2[mi][rg], off);
        top2merge(rs1[mi][rg], rs2[mi][rg], o1, o2);
      }
  }
  if (l15 == 0) {
    #pragma unroll
    for (int mi = 0; mi < 8; ++mi)
      #pragma unroll
      for (int rg = 0; rg < 4; ++rg)
        partR[((size_t)(cs * 4 + wn) * B_ + b) * N_ + r0 + mi * 16 + g * 4 + rg] =
            make_uint2(__float_as_uint(rs1[mi][rg]), __float_as_uint(rs2[mi][rg]));
  }
}

// ---- fold partials, decode, ratio test ----
__global__ __launch_bounds__(256)
void merge_kernel(const uint2* __restrict__ pR, const uint2* __restrict__ pC,
                  int* __restrict__ m0, float* __restrict__ s0, int* __restrict__ m1)
{
  const int tid = blockIdx.x * 256 + threadIdx.x;
  if (tid >= 2 * B_ * N_) return;
  const int dir = tid >> 15;
  const int i = tid & (B_ * N_ - 1);
  const float NEG = __uint_as_float(0xFF800000u);

  if (dir == 0) {
    float s1 = NEG, s2 = NEG; int bs = 0;
    #pragma unroll
    for (int sl = 0; sl < 16; ++sl) {
      const uint2 v = pR[(size_t)sl * B_ * N_ + i];
      const float o1 = __uint_as_float(v.x), o2 = __uint_as_float(v.y);
      bs = (o1 > s1) ? sl : bs;
      top2merge(s1, s2, o1, o2);
    }
    const uint k1 = __float_as_uint(s1);
    const int col = (bs >> 2) * 1024 + 1023 - (int)(k1 & 0x3FFu);
    const float v1 = __uint_as_float(k1 & 0xFFFFFC00u);
    const float v2 = __uint_as_float(__float_as_uint(s2) & 0xFFFFFC00u);
    const bool ok = (1.0f - v1) <= 0.64f * (1.0f - v2);
    m0[i] = ok ? col : -1;
    s0[i] = ok ? (v1 + 1.0f) * 0.5f : 0.0f;
  } else {
    float s1 = NEG, s2 = NEG; int bs = 0;
    #pragma unroll 8
    for (int sl = 0; sl < 32; ++sl) {
      const uint2 v = pC[(size_t)sl * B_ * N_ + i];
      const float o1 = __uint_as_float(v.x), o2 = __uint_as_float(v.y);
      bs = (o1 > s1) ? sl : bs;
      top2merge(s1, s2, o1, o2);
    }
    const uint k1 = __float_as_uint(s1);
    const int row = bs * 128 + 127 - (int)(k1 & 0x7Fu);
    const float v1 = __uint_as_float(k1 & 0xFFFFFF00u);
    const float v2 = __uint_as_float(__float_as_uint(s2) & 0xFFFFFF00u);
    const bool ok = (1.0f - v1) <= 0.64f * (1.0f - v2);
    m1[i] = ok ? row : -1;
  }
}

// ---- mutual check + output ----
__global__ __launch_bounds__(256)
void finalize_kernel(const int* __restrict__ m0, const float* __restrict__ s0,
                     const int* __restrict__ m1, float* __restrict__ out)
{
  const int idx = blockIdx.x * 256 + threadIdx.x;
  if (idx >= B_ * N_) return;
  const int b = idx >> 12;
  const int n = idx & (N_ - 1);
  const int mm = m0[idx];
  int res = -1;
  if (mm > -1 && m1[((size_t)b << 12) + mm] == n) res = mm;
  out[idx] = (float)res;
  out[B_ * N_ + idx] = s0[idx];
}

extern "C" void kernel_launch(void* const* d_in, const int* in_sizes, int n_in,
                              void* d_out, int out_size, void* d_ws, size_t ws_size,
                              hipStream_t stream)
{
  const float* d0 = (const float*)d_in[0];
  const float* d1 = (const float*)d_in[1];
  float* out = (float*)d_out;

  ushort_t* At = (ushort_t*)((char*)d_ws + OFF_AT);
  ushort_t* Bt = (ushort_t*)((char*)d_ws + OFF_BT);
  uint2* PR = (uint2*)((char*)d_ws + OFF_PR);
  uint2* PC = (uint2*)((char*)d_ws + OFF_PC);
  int*   m0 = (int*)  ((char*)d_ws + OFF_M0);
  float* s0 = (float*)((char*)d_ws + OFF_S0);
  int*   m1 = (int*)  ((char*)d_ws + OFF_M1);

  prep_kernel<<<dim3(N_ / 32, D_ / 32, 16), 256, 0, stream>>>(d0, d1, At, Bt);
  nn_pass<<<dim3(B_ * (N_ / BM) * CSPLIT), 256, 0, stream>>>(At, Bt, PR, PC);
  merge_kernel<<<dim3(2 * B_ * N_ / 256), 256, 0, stream>>>(PR, PC, m0, s0, m1);
  finalize_kernel<<<dim3(B_ * N_ / 256), 256, 0, stream>>>(m0, s0, m1, out);
}